// Round 3
// baseline (200.676 us; speedup 1.0000x reference)
//
#include <hip/hip_runtime.h>

// AttentionHead: B=4, S=2048, D=1024, fp32 in/out, bf16 MFMA compute.
// GEMM core: 256x256 tile, BK=32, 8 waves (2Mx4N), ring-4 LDS pipeline,
// counted vmcnt(8) (never 0 in steady state), setprio around MFMA.

typedef __attribute__((ext_vector_type(8))) short short8;
typedef __attribute__((ext_vector_type(4))) float floatx4;

static constexpr long long XE = 8388608LL;  // 4*2048*1024
static constexpr long long WE = 1048576LL;  // 1024*1024

static __device__ __forceinline__ unsigned short f2b(float f) {
  unsigned u = __builtin_bit_cast(unsigned, f);
  u = (u + 0x7fffu + ((u >> 16) & 1u)) >> 16;
  return (unsigned short)u;
}

static __device__ __forceinline__ void gload16(const unsigned short* g, unsigned short* l) {
  __builtin_amdgcn_global_load_lds(
      (const __attribute__((address_space(1))) unsigned int*)g,
      (__attribute__((address_space(3))) unsigned int*)l, 16, 0, 0);
}

static __device__ __forceinline__ void sbar() {
  asm volatile("" ::: "memory");
  __builtin_amdgcn_s_barrier();
  asm volatile("" ::: "memory");
}

#define VMCNT(n) asm volatile("s_waitcnt vmcnt(" #n ")" ::: "memory")

// OUTMODE 0: bf16 ; 1: fp32. A [M][K] row-major, Bt [N][K] row-major.
// Ring slot r (32 KB): A-tile bytes [r*32768, +16384), B-tile next 16384.
// LDS linear chunk ci (16B) of a tile holds global chunk (ci&3)^((ci>>2>>1)&3)
// of row ci>>2 (pre-swizzled global source; linear gload dest; swizzled read).
template <int OUTMODE>
static __device__ __forceinline__ void gemm256(
    const unsigned short* __restrict__ A, const unsigned short* __restrict__ Bt,
    void* __restrict__ Cv, int lda, int ldb, int ldc, int nk, float scale,
    int bi, int bj, char* sb) {
  const int tid = threadIdx.x;
  const int wave = tid >> 6, lane = tid & 63;
  const int wm = wave >> 2, wn = wave & 3;
  const int frow = lane & 15, hi = lane >> 4;

  // staging source decomposition (2 loads per tile per matrix per thread)
  const int ci0 = tid, ci1 = 512 + tid;
  const int sr0 = ci0 >> 2, sr1 = ci1 >> 2;
  const int sc0 = ((ci0 & 3) ^ ((sr0 >> 1) & 3)) * 8;
  const int sc1 = ((ci1 & 3) ^ ((sr1 >> 1) & 3)) * 8;
  const unsigned short* gA0 = A + (long long)(bi * 256 + sr0) * lda + sc0;
  const unsigned short* gA1 = A + (long long)(bi * 256 + sr1) * lda + sc1;
  const unsigned short* gB0 = Bt + (long long)(bj * 256 + sr0) * ldb + sc0;
  const unsigned short* gB1 = Bt + (long long)(bj * 256 + sr1) * ldb + sc1;

  // LDS dests (wave-uniform base; HW adds lane*16)
  const int dA0 = wave * 1024, dA1 = 8192 + wave * 1024;

  // fragment read offsets
  const int rch = (hi ^ ((frow >> 1) & 3)) * 16;
  const int aoff = (wm * 128 + frow) * 64 + rch;
  const int boff = 16384 + (wn * 64 + frow) * 64 + rch;

  // prologue: stage tiles 0,1,2 (12 wave-loads), wait tile 0 (vmcnt 8)
#pragma unroll
  for (int tt = 0; tt < 3; ++tt) {
    const int so = tt * 32768, ko = tt * 32;
    gload16(gA0 + ko, (unsigned short*)(sb + so + dA0));
    gload16(gA1 + ko, (unsigned short*)(sb + so + dA1));
    gload16(gB0 + ko, (unsigned short*)(sb + so + 16384 + dA0));
    gload16(gB1 + ko, (unsigned short*)(sb + so + 16384 + dA1));
  }
  VMCNT(8);
  __builtin_amdgcn_s_barrier();
  asm volatile("" ::: "memory");

  const unsigned short* pA0 = gA0 + 96;
  const unsigned short* pA1 = gA1 + 96;
  const unsigned short* pB0 = gB0 + 96;
  const unsigned short* pB1 = gB1 + 96;

  floatx4 acc[8][4] = {};

  for (int t = 0; t < nk; ++t) {
    const int slot = (t & 3) * 32768;
    const int sst = ((t + 3) & 3) * 32768;
    const bool st = (t + 3) < nk;
    // ---- phase A: issue A(t+3), read m0-3 + n0-3, 16 MFMA
    if (st) {
      gload16(pA0, (unsigned short*)(sb + sst + dA0));
      gload16(pA1, (unsigned short*)(sb + sst + dA1));
    }
    short8 af[4], bf[4];
#pragma unroll
    for (int m = 0; m < 4; ++m)
      af[m] = *(const short8*)(sb + slot + aoff + m * 1024);
#pragma unroll
    for (int n = 0; n < 4; ++n)
      bf[n] = *(const short8*)(sb + slot + boff + n * 1024);
    __builtin_amdgcn_s_setprio(1);
#pragma unroll
    for (int m = 0; m < 4; ++m)
#pragma unroll
      for (int n = 0; n < 4; ++n)
        acc[m][n] = __builtin_amdgcn_mfma_f32_16x16x32_bf16(af[m], bf[n], acc[m][n], 0, 0, 0);
    __builtin_amdgcn_s_setprio(0);
    sbar();
    // ---- phase B: issue B(t+3), read m4-7, 16 MFMA
    if (st) {
      gload16(pB0, (unsigned short*)(sb + sst + 16384 + dA0));
      gload16(pB1, (unsigned short*)(sb + sst + 16384 + dA1));
    }
#pragma unroll
    for (int m = 0; m < 4; ++m)
      af[m] = *(const short8*)(sb + slot + aoff + (m + 4) * 1024);
    __builtin_amdgcn_s_setprio(1);
#pragma unroll
    for (int m = 0; m < 4; ++m)
#pragma unroll
      for (int n = 0; n < 4; ++n)
        acc[m + 4][n] = __builtin_amdgcn_mfma_f32_16x16x32_bf16(af[m], bf[n], acc[m + 4][n], 0, 0, 0);
    __builtin_amdgcn_s_setprio(0);
    pA0 += 32; pA1 += 32; pB0 += 32; pB1 += 32;
    // counted waits: steady 8, tail 4 -> 0 (uniform conditions)
    if (t + 4 <= nk)      { VMCNT(8); }
    else if (t + 3 == nk) { VMCNT(4); }
    else if (t + 2 == nk) { VMCNT(0); }
    __builtin_amdgcn_s_barrier();
    asm volatile("" ::: "memory");
  }

  // C/D: col = lane&15 (+n*16), row = hi*4 + j (+m*16)
  const long long crow0 = (long long)bi * 256 + wm * 128 + hi * 4;
  const int ccol = bj * 256 + wn * 64 + frow;
  if constexpr (OUTMODE == 0) {
    unsigned short* C = (unsigned short*)Cv;
#pragma unroll
    for (int m = 0; m < 8; ++m)
#pragma unroll
      for (int j = 0; j < 4; ++j) {
        unsigned short* cp = C + (crow0 + m * 16 + j) * (long long)ldc + ccol;
#pragma unroll
        for (int n = 0; n < 4; ++n) cp[n * 16] = f2b(acc[m][n][j] * scale);
      }
  } else {
    float* C = (float*)Cv;
#pragma unroll
    for (int m = 0; m < 8; ++m)
#pragma unroll
      for (int j = 0; j < 4; ++j) {
        float* cp = C + (crow0 + m * 16 + j) * (long long)ldc + ccol;
#pragma unroll
        for (int n = 0; n < 4; ++n) cp[n * 16] = acc[m][n][j] * scale;
      }
  }
}

// z=0: K = Xk@Wk ; z=1: V^T = Wv^T @ Xv^T (operand swap) ; z=2: Q = Xq@Wq
__global__ __launch_bounds__(512, 2) void proj_kernel(
    const unsigned short* __restrict__ Xb, const unsigned short* __restrict__ Wt,
    unsigned short* __restrict__ Kb, unsigned short* __restrict__ Vt,
    unsigned short* __restrict__ Qb) {
  extern __shared__ char smem[];
  const int z = blockIdx.z;
  const unsigned short* A;
  const unsigned short* B;
  unsigned short* C;
  int ldc, bi, bj;
  if (z == 1) {
    A = Wt + WE; B = Xb + XE; C = Vt; ldc = 8192;
    bi = blockIdx.y; bj = blockIdx.x;  // M=1024 (4 tiles), N=8192 (32 tiles)
  } else {
    A = Xb + (z ? 2 * XE : 0); B = Wt + (z ? 2 * WE : 0);
    C = z ? Qb : Kb; ldc = 1024;
    bi = blockIdx.x; bj = blockIdx.y;  // M=8192 (32), N=1024 (4)
  }
  gemm256<0>(A, B, C, 1024, 1024, ldc, 32, 1.f, bi, bj, smem);
}

// lower-triangular 256-tiles, all batches: grid (36, 4)
__global__ __launch_bounds__(512, 2) void scores_kernel(
    const unsigned short* __restrict__ Qb, const unsigned short* __restrict__ Kb,
    float* __restrict__ S) {
  extern __shared__ char smem[];
  int t = blockIdx.x, bi = 0;
  while ((bi + 1) * (bi + 2) / 2 <= t) ++bi;
  const int bj = t - bi * (bi + 1) / 2;
  const long long b = blockIdx.y;
  gemm256<1>(Qb + b * 2048 * 1024, Kb + b * 2048 * 1024, S + b * 2048 * 2048,
             1024, 1024, 2048, 32, 0.03125f, bi, bj, smem);
}

// O = P V ; P bf16 in-place over S rows (lda 4096), K-limit (bi+1)*256.
__global__ __launch_bounds__(512, 2) void pv_kernel(
    const unsigned short* __restrict__ P, const unsigned short* __restrict__ Vt,
    float* __restrict__ out) {
  extern __shared__ char smem[];
  const int b = blockIdx.x >> 2, bj = blockIdx.x & 3;
  const int bi = 7 - blockIdx.y;  // heavy tiles first
  gemm256<1>(P + (long long)b * 2048 * 4096, Vt + (long long)b * 2048,
             out + (long long)b * 2048 * 1024,
             4096, 8192, 1024, (bi + 1) * 8, 1.f, bi, bj, smem);
}

// fused fp32->bf16 convert of the three activations: grid (1024, 3)
__global__ __launch_bounds__(256) void cvt3(
    const float* __restrict__ X0, const float* __restrict__ X1,
    const float* __restrict__ X2, unsigned short* __restrict__ Xb) {
  const float* in = blockIdx.y == 0 ? X0 : (blockIdx.y == 1 ? X1 : X2);
  unsigned short* out = Xb + (long long)blockIdx.y * XE;
  const int n4 = (int)(XE / 4);
  const int stride = 1024 * 256;
  for (int i = blockIdx.x * 256 + threadIdx.x; i < n4; i += stride) {
    float4 x = ((const float4*)in)[i];
    ushort4 o;
    o.x = f2b(x.x); o.y = f2b(x.y); o.z = f2b(x.z); o.w = f2b(x.w);
    ((ushort4*)out)[i] = o;
  }
}

// W [1024][1024] fp32 (i,o) -> Wt bf16 [o][i]
__global__ __launch_bounds__(256) void wcvt_t(
    const float* __restrict__ W0, const float* __restrict__ W1,
    const float* __restrict__ W2, unsigned short* __restrict__ Wt) {
  const float* W = blockIdx.z == 0 ? W0 : (blockIdx.z == 1 ? W1 : W2);
  unsigned short* dst = Wt + (long long)blockIdx.z * WE;
  __shared__ unsigned short tile[64][65];
  const int t = threadIdx.x;
  const int i0 = blockIdx.x * 64, j0 = blockIdx.y * 64;
#pragma unroll
  for (int r = 0; r < 16; ++r) {
    int lin = r * 256 + t;
    int i = lin >> 6, j = lin & 63;
    tile[i][j] = f2b(W[(long long)(i0 + i) * 1024 + j0 + j]);
  }
  __syncthreads();
#pragma unroll
  for (int r = 0; r < 16; ++r) {
    int lin = r * 256 + t;
    int o = lin >> 6, i = lin & 63;
    dst[(long long)(j0 + o) * 1024 + i0 + i] = tile[i][o];
  }
}

// one wave per row; causal mask; writes bf16 P in-place over the fp32 row.
__global__ __launch_bounds__(256) void softmax_causal(float* __restrict__ Sb) {
  const int row = blockIdx.x * 4 + (threadIdx.x >> 6);
  const int lane = threadIdx.x & 63;
  const int q = row & 2047;
  const float4* src = (const float4*)(Sb + (long long)row * 2048);
  float v[32];
#pragma unroll
  for (int g = 0; g < 8; ++g) {
    float4 x = src[g * 64 + lane];
    const int c0 = g * 256 + lane * 4;
    v[g * 4 + 0] = (c0 + 0 <= q) ? x.x : -1e30f;
    v[g * 4 + 1] = (c0 + 1 <= q) ? x.y : -1e30f;
    v[g * 4 + 2] = (c0 + 2 <= q) ? x.z : -1e30f;
    v[g * 4 + 3] = (c0 + 3 <= q) ? x.w : -1e30f;
  }
  float mx = -1e30f;
#pragma unroll
  for (int i = 0; i < 32; ++i) mx = fmaxf(mx, v[i]);
  for (int off = 32; off; off >>= 1) mx = fmaxf(mx, __shfl_xor(mx, off));
  float s = 0.f;
#pragma unroll
  for (int i = 0; i < 32; ++i) {
    float e = (v[i] > -1e29f) ? __expf(v[i] - mx) : 0.f;
    v[i] = e; s += e;
  }
  for (int off = 32; off; off >>= 1) s += __shfl_xor(s, off);
  const float inv = 1.f / s;
  asm volatile("" ::: "memory");
  unsigned short* dst = (unsigned short*)Sb + (long long)row * 4096;
#pragma unroll
  for (int g = 0; g < 8; ++g) {
    ushort4 o;
    o.x = f2b(v[g * 4 + 0] * inv);
    o.y = f2b(v[g * 4 + 1] * inv);
    o.z = f2b(v[g * 4 + 2] * inv);
    o.w = f2b(v[g * 4 + 3] * inv);
    ((ushort4*)dst)[g * 64 + lane] = o;
  }
}

extern "C" void kernel_launch(void* const* d_in, const int* in_sizes, int n_in,
                              void* d_out, int out_size, void* d_ws, size_t ws_size,
                              hipStream_t stream) {
  const float* Xk = (const float*)d_in[0];
  const float* Xv = (const float*)d_in[1];
  const float* Xq = (const float*)d_in[2];
  const float* Wk = (const float*)d_in[3];
  const float* Wv = (const float*)d_in[4];
  const float* Wq = (const float*)d_in[5];
  float* out = (float*)d_out;

  // ws (ushort elems): S fp32 [0, 33.5M ushorts) aliases Wt+Xb (dead after proj);
  // then Qb | Kb | Vt. Peak 117.4 MB.
  unsigned short* ws = (unsigned short*)d_ws;
  float* S = (float*)d_ws;
  unsigned short* Wt = ws;
  unsigned short* Xb = ws + 3 * WE;
  unsigned short* Qb = ws + 33554432LL;
  unsigned short* Kb = Qb + XE;
  unsigned short* Vt = Kb + XE;

  cvt3<<<dim3(1024, 3), 256, 0, stream>>>(Xk, Xv, Xq, Xb);
  wcvt_t<<<dim3(16, 16, 3), 256, 0, stream>>>(Wk, Wv, Wq, Wt);

  proj_kernel<<<dim3(32, 4, 3), 512, 131072, stream>>>(Xb, Wt, Kb, Vt, Qb);
  scores_kernel<<<dim3(36, 4), 512, 131072, stream>>>(Qb, Kb, S);
  softmax_causal<<<2048, 256, 0, stream>>>(S);
  pv_kernel<<<dim3(16, 8), 512, 131072, stream>>>((const unsigned short*)d_ws, Vt, out);
}

// Round 4
// 188.303 us; speedup vs baseline: 1.0657x; 1.0657x over previous
//
#include <hip/hip_runtime.h>

// AttentionHead: B=4, S=2048, D=1024, fp32 in/out, bf16 MFMA compute.
// proj: 256x256 8-phase pipelined GEMM (m201 template, plain HIP).
// scores/pv: proven 128x128 2-barrier core. softmax in-place fp32->bf16.

typedef __attribute__((ext_vector_type(8))) short short8;
typedef __attribute__((ext_vector_type(4))) float floatx4;

static constexpr long long XE = 8388608LL;  // 4*2048*1024
static constexpr long long WE = 1048576LL;  // 1024*1024

static __device__ __forceinline__ unsigned short f2b(float f) {
  unsigned u = __builtin_bit_cast(unsigned, f);
  u = (u + 0x7fffu + ((u >> 16) & 1u)) >> 16;
  return (unsigned short)u;
}

static __device__ __forceinline__ void gload16(const unsigned short* g, unsigned short* l) {
  __builtin_amdgcn_global_load_lds(
      (const __attribute__((address_space(1))) unsigned int*)g,
      (__attribute__((address_space(3))) unsigned int*)l, 16, 0, 0);
}

#define VMCNT(n) asm volatile("s_waitcnt vmcnt(" #n ")" ::: "memory")
#define LGKM0() asm volatile("s_waitcnt lgkmcnt(0)" ::: "memory")
#define BARRIER() do { asm volatile("" ::: "memory"); __builtin_amdgcn_s_barrier(); asm volatile("" ::: "memory"); } while (0)

// ================== proj: 256x256, BK=64, 8-wave, 8-phase ==================
// LDS slot s (64KB): A-tile [s*65536, +32768), B-tile [+32768, +32768).
// Tile row = 128B = 8 chunks of 16B; LDS chunk p of row r holds global chunk
// p^(r&7) (pre-swizzled global source, linear gload dest, swizzled read).

#define STAGE(base, matoff, h, slot, kt) do {                                  \
    const unsigned short* _s = (base) + (h) * 131072 + (kt) * 64;              \
    char* _d = sb + (slot) * 65536 + (matoff) + (h) * 16384 + dwave;           \
    gload16(_s, (unsigned short*)_d);                                          \
    gload16(_s + 65536, (unsigned short*)(_d + 8192));                         \
  } while (0)

#define READ_A(slot, mb) do {                                                  \
    const char* _p = sb + (slot) * 65536 + aoffb + (mb) * 2048;                \
    af[0][0] = *(const short8*)(_p + c0);        af[0][1] = *(const short8*)(_p + c1); \
    af[1][0] = *(const short8*)(_p + 2048 + c0); af[1][1] = *(const short8*)(_p + 2048 + c1); \
    af[2][0] = *(const short8*)(_p + 4096 + c0); af[2][1] = *(const short8*)(_p + 4096 + c1); \
    af[3][0] = *(const short8*)(_p + 6144 + c0); af[3][1] = *(const short8*)(_p + 6144 + c1); \
  } while (0)

#define READ_B(slot, nb, bfx) do {                                             \
    const char* _p = sb + (slot) * 65536 + boffb + (nb) * 2048;                \
    bfx[0][0] = *(const short8*)(_p + c0);        bfx[0][1] = *(const short8*)(_p + c1); \
    bfx[1][0] = *(const short8*)(_p + 2048 + c0); bfx[1][1] = *(const short8*)(_p + 2048 + c1); \
  } while (0)

#define MF16(MB, NB, bfx) do {                                                 \
    __builtin_amdgcn_s_setprio(1);                                             \
    _Pragma("unroll")                                                          \
    for (int _m = 0; _m < 4; ++_m) {                                           \
      _Pragma("unroll")                                                        \
      for (int _n = 0; _n < 2; ++_n) {                                         \
        acc[(MB) + _m][(NB) + _n] = __builtin_amdgcn_mfma_f32_16x16x32_bf16(   \
            af[_m][0], bfx[_n][0], acc[(MB) + _m][(NB) + _n], 0, 0, 0);        \
        acc[(MB) + _m][(NB) + _n] = __builtin_amdgcn_mfma_f32_16x16x32_bf16(   \
            af[_m][1], bfx[_n][1], acc[(MB) + _m][(NB) + _n], 0, 0, 0);        \
      } }                                                                      \
    __builtin_amdgcn_s_setprio(0);                                             \
  } while (0)

// z=0: K = Xk@Wk ; z=1: V^T = Wv^T @ Xv^T (operand swap) ; z=2: Q = Xq@Wq
__global__ __launch_bounds__(512, 2) void proj8_kernel(
    const unsigned short* __restrict__ Xb, const unsigned short* __restrict__ Wt,
    unsigned short* __restrict__ Kb, unsigned short* __restrict__ Vt,
    unsigned short* __restrict__ Qb) {
  extern __shared__ char sb[];
  const int z = blockIdx.z;
  const unsigned short *Aop, *Bop;
  unsigned short* C;
  int ldc, bi, bj;
  if (z == 1) {
    Aop = Wt + WE; Bop = Xb + XE; C = Vt; ldc = 8192;
    bi = blockIdx.y; bj = blockIdx.x;  // M=1024 (4 tiles), N=8192 (32 tiles)
  } else {
    Aop = Xb + (z ? 2 * XE : 0); Bop = Wt + (z ? 2 * WE : 0);
    C = z ? Qb : Kb; ldc = 1024;
    bi = blockIdx.x; bj = blockIdx.y;  // M=8192 (32), N=1024 (4)
  }

  const int tid = threadIdx.x, wave = tid >> 6, lane = tid & 63;
  const int wm = wave >> 2, wn = wave & 3, frow = lane & 15, hi = lane >> 4;
  const int r0 = tid >> 3, p0 = ((tid & 7) ^ (r0 & 7)) * 8;
  const int dwave = wave * 1024;
  const int sx = frow & 7;
  const int c0 = (hi ^ sx) * 16, c1 = ((4 + hi) ^ sx) * 16;
  const int aoffb = (wm * 128 + frow) * 128;
  const int boffb = 32768 + (wn * 64 + frow) * 128;
  const unsigned short* Ab = Aop + (long long)(bi * 256 + r0) * 1024 + p0;
  const unsigned short* Bb = Bop + (long long)(bj * 256 + r0) * 1024 + p0;

  short8 af[4][2], bf0[2][2], bf1[2][2];
  floatx4 acc[8][4] = {};

  // prologue: As0 h0,h1 (kt0) ; Bs0 h0,h1 (kt0) ; Bs1 h0,h1 (kt1)
  STAGE(Ab, 0, 0, 0, 0);     STAGE(Ab, 0, 1, 0, 0);
  STAGE(Bb, 32768, 0, 0, 0); STAGE(Bb, 32768, 1, 0, 0);
  STAGE(Bb, 32768, 0, 1, 1); STAGE(Bb, 32768, 1, 1, 1);
  VMCNT(4);
  BARRIER();

  for (int t = 0; t < 8; ++t) {
    const int kt1 = 2 * t + 1, kt2 = 2 * t + 2, kt3 = 2 * t + 3;
    const bool pf = t < 7;
    // ph1: quadrant (m0-3, n0-1) of slot0 ; prefetch A-slot1 h0 (kt1)
    READ_A(0, 0); READ_B(0, 0, bf0);
    STAGE(Ab, 0, 0, 1, kt1);
    BARRIER(); LGKM0();
    MF16(0, 0, bf0);
    BARRIER();
    // ph2: (m0-3, n2-3) ; prefetch A-slot1 h1
    READ_B(0, 2, bf1);
    STAGE(Ab, 0, 1, 1, kt1);
    BARRIER(); LGKM0();
    MF16(0, 2, bf1);
    BARRIER();
    // ph3: (m4-7, n2-3) ; prefetch B-slot0 h0 (kt2)
    READ_A(0, 4);
    if (pf) STAGE(Bb, 32768, 0, 0, kt2);
    BARRIER(); LGKM0();
    MF16(4, 2, bf1);
    BARRIER();
    // ph4: (m4-7, n0-1, reuse) ; prefetch B-slot0 h1 ; counted vmcnt
    if (pf) STAGE(Bb, 32768, 1, 0, kt2);
    BARRIER();
    MF16(4, 0, bf0);
    if (pf) { VMCNT(4); } else { VMCNT(0); }
    BARRIER();
    // ph5: slot1 (m0-3, n0-1) ; prefetch A-slot0 h0 (kt2)
    READ_A(1, 0); READ_B(1, 0, bf0);
    if (pf) STAGE(Ab, 0, 0, 0, kt2);
    BARRIER(); LGKM0();
    MF16(0, 0, bf0);
    BARRIER();
    // ph6: (m0-3, n2-3) ; prefetch A-slot0 h1
    READ_B(1, 2, bf1);
    if (pf) STAGE(Ab, 0, 1, 0, kt2);
    BARRIER(); LGKM0();
    MF16(0, 2, bf1);
    BARRIER();
    // ph7: (m4-7, n2-3) ; prefetch B-slot1 h0 (kt3)
    READ_A(1, 4);
    if (pf) STAGE(Bb, 32768, 0, 1, kt3);
    BARRIER(); LGKM0();
    MF16(4, 2, bf1);
    BARRIER();
    // ph8: (m4-7, n0-1, reuse) ; prefetch B-slot1 h1 ; counted vmcnt
    if (pf) STAGE(Bb, 32768, 1, 1, kt3);
    BARRIER();
    MF16(4, 0, bf0);
    if (pf) { VMCNT(4); } else { VMCNT(0); }
    BARRIER();
  }

  // C/D: col = lane&15 (+n*16), row = hi*4 + j (+m*16)
  const long long crow0 = (long long)bi * 256 + wm * 128 + hi * 4;
  const int ccol = bj * 256 + wn * 64 + frow;
#pragma unroll
  for (int m = 0; m < 8; ++m)
#pragma unroll
    for (int j = 0; j < 4; ++j) {
      unsigned short* cp = C + (crow0 + m * 16 + j) * (long long)ldc + ccol;
#pragma unroll
      for (int n = 0; n < 4; ++n) cp[n * 16] = f2b(acc[m][n][j]);
    }
}

// ================== round-2 proven 128x128 core (scores/pv) ==================
template <bool BF16OUT>
static __device__ __forceinline__ void gemm_core(
    const unsigned short* __restrict__ A, const unsigned short* __restrict__ Bt,
    int lda, int ldb, int nk, void* __restrict__ Cv, int ldc, float scale,
    int bi, int bj) {
  __shared__ __align__(16) unsigned short lA[128 * 64];
  __shared__ __align__(16) unsigned short lB[128 * 64];
  const int t = threadIdx.x, wave = t >> 6, lane = t & 63;
  const int wr = wave >> 1, wc = wave & 1;
  const int sr = lane >> 3;
  const int sc = ((lane & 7) ^ sr) * 8;
  const unsigned short* gA = A + (long long)(bi * 128 + wave * 32 + sr) * lda + sc;
  const unsigned short* gB = Bt + (long long)(bj * 128 + wave * 32 + sr) * ldb + sc;
  unsigned short* lAw = lA + wave * 2048;
  unsigned short* lBw = lB + wave * 2048;
  const int frow = lane & 15, hi = lane >> 4;

  floatx4 acc[4][4] = {};
  for (int ks = 0; ks < nk; ++ks) {
    const long long k0 = (long long)ks * 64;
    __syncthreads();
#pragma unroll
    for (int g = 0; g < 4; ++g) {
      gload16(gA + (long long)g * 8 * lda + k0, lAw + g * 512);
      gload16(gB + (long long)g * 8 * ldb + k0, lBw + g * 512);
    }
    __syncthreads();
#pragma unroll
    for (int kk = 0; kk < 2; ++kk) {
      const int ch = (kk * 4 + hi) ^ (frow & 7);
      short8 af[4], bf[4];
#pragma unroll
      for (int m = 0; m < 4; ++m)
        af[m] = *(const short8*)&lA[(wr * 64 + m * 16 + frow) * 64 + ch * 8];
#pragma unroll
      for (int n = 0; n < 4; ++n)
        bf[n] = *(const short8*)&lB[(wc * 64 + n * 16 + frow) * 64 + ch * 8];
#pragma unroll
      for (int m = 0; m < 4; ++m)
#pragma unroll
        for (int n = 0; n < 4; ++n)
          acc[m][n] = __builtin_amdgcn_mfma_f32_16x16x32_bf16(af[m], bf[n], acc[m][n], 0, 0, 0);
    }
  }

  const long long crow0 = (long long)bi * 128 + wr * 64 + hi * 4;
  const int ccol = bj * 128 + wc * 64 + frow;
  if constexpr (BF16OUT) {
    unsigned short* C = (unsigned short*)Cv;
#pragma unroll
    for (int m = 0; m < 4; ++m)
#pragma unroll
      for (int j = 0; j < 4; ++j) {
        unsigned short* cp = C + (crow0 + m * 16 + j) * (long long)ldc + ccol;
#pragma unroll
        for (int n = 0; n < 4; ++n) cp[n * 16] = f2b(acc[m][n][j] * scale);
      }
  } else {
    float* C = (float*)Cv;
#pragma unroll
    for (int m = 0; m < 4; ++m)
#pragma unroll
      for (int j = 0; j < 4; ++j) {
        float* cp = C + (crow0 + m * 16 + j) * (long long)ldc + ccol;
#pragma unroll
        for (int n = 0; n < 4; ++n) cp[n * 16] = acc[m][n][j] * scale;
      }
  }
}

// lower-triangular 128-tiles, all batches: grid (136, 4)
__global__ __launch_bounds__(256) void scores_kernel(
    const unsigned short* __restrict__ Qb, const unsigned short* __restrict__ Kb,
    float* __restrict__ S) {
  int t = blockIdx.x, bi = 0;
  while ((bi + 1) * (bi + 2) / 2 <= t) ++bi;
  const int bj = t - bi * (bi + 1) / 2;
  const long long b = blockIdx.y;
  gemm_core<false>(Qb + b * 2048 * 1024, Kb + b * 2048 * 1024, 1024, 1024, 16,
                   S + b * 2048 * 2048, 2048, 0.03125f, bi, bj);
}

// O = P V ; P bf16 in-place over S rows (lda 4096), K-limit (bi+1)*128.
__global__ __launch_bounds__(256) void pv_kernel(
    const unsigned short* __restrict__ P, const unsigned short* __restrict__ Vt,
    float* __restrict__ out) {
  const int b = blockIdx.x >> 3, bj = blockIdx.x & 7;
  const int bi = 15 - blockIdx.y;  // heavy tiles first
  gemm_core<false>(P + (long long)b * 2048 * 4096, Vt + (long long)b * 2048,
                   4096, 8192, (bi + 1) * 2,
                   out + (long long)b * 2048 * 1024, 1024, 1.f, bi, bj);
}

// fused fp32->bf16 convert of the three activations: grid (1024, 3)
__global__ __launch_bounds__(256) void cvt3(
    const float* __restrict__ X0, const float* __restrict__ X1,
    const float* __restrict__ X2, unsigned short* __restrict__ Xb) {
  const float* in = blockIdx.y == 0 ? X0 : (blockIdx.y == 1 ? X1 : X2);
  unsigned short* out = Xb + (long long)blockIdx.y * XE;
  const int n4 = (int)(XE / 4);
  const int stride = 1024 * 256;
  for (int i = blockIdx.x * 256 + threadIdx.x; i < n4; i += stride) {
    float4 x = ((const float4*)in)[i];
    ushort4 o;
    o.x = f2b(x.x); o.y = f2b(x.y); o.z = f2b(x.z); o.w = f2b(x.w);
    ((ushort4*)out)[i] = o;
  }
}

// W [1024][1024] fp32 (i,o) -> Wt bf16 [o][i]
__global__ __launch_bounds__(256) void wcvt_t(
    const float* __restrict__ W0, const float* __restrict__ W1,
    const float* __restrict__ W2, unsigned short* __restrict__ Wt) {
  const float* W = blockIdx.z == 0 ? W0 : (blockIdx.z == 1 ? W1 : W2);
  unsigned short* dst = Wt + (long long)blockIdx.z * WE;
  __shared__ unsigned short tile[64][65];
  const int t = threadIdx.x;
  const int i0 = blockIdx.x * 64, j0 = blockIdx.y * 64;
#pragma unroll
  for (int r = 0; r < 16; ++r) {
    int lin = r * 256 + t;
    int i = lin >> 6, j = lin & 63;
    tile[i][j] = f2b(W[(long long)(i0 + i) * 1024 + j0 + j]);
  }
  __syncthreads();
#pragma unroll
  for (int r = 0; r < 16; ++r) {
    int lin = r * 256 + t;
    int o = lin >> 6, i = lin & 63;
    dst[(long long)(j0 + o) * 1024 + i0 + i] = tile[i][o];
  }
}

// one wave per row; causal mask; writes bf16 P in-place over the fp32 row.
__global__ __launch_bounds__(256) void softmax_causal(float* __restrict__ Sb) {
  const int row = blockIdx.x * 4 + (threadIdx.x >> 6);
  const int lane = threadIdx.x & 63;
  const int q = row & 2047;
  const float4* src = (const float4*)(Sb + (long long)row * 2048);
  float v[32];
#pragma unroll
  for (int g = 0; g < 8; ++g) {
    float4 x = src[g * 64 + lane];
    const int c0 = g * 256 + lane * 4;
    v[g * 4 + 0] = (c0 + 0 <= q) ? x.x : -1e30f;
    v[g * 4 + 1] = (c0 + 1 <= q) ? x.y : -1e30f;
    v[g * 4 + 2] = (c0 + 2 <= q) ? x.z : -1e30f;
    v[g * 4 + 3] = (c0 + 3 <= q) ? x.w : -1e30f;
  }
  float mx = -1e30f;
#pragma unroll
  for (int i = 0; i < 32; ++i) mx = fmaxf(mx, v[i]);
  for (int off = 32; off; off >>= 1) mx = fmaxf(mx, __shfl_xor(mx, off));
  float s = 0.f;
#pragma unroll
  for (int i = 0; i < 32; ++i) {
    float e = (v[i] > -1e29f) ? __expf(v[i] - mx) : 0.f;
    v[i] = e; s += e;
  }
  for (int off = 32; off; off >>= 1) s += __shfl_xor(s, off);
  const float inv = 1.f / s;
  asm volatile("" ::: "memory");
  unsigned short* dst = (unsigned short*)Sb + (long long)row * 4096;
#pragma unroll
  for (int g = 0; g < 8; ++g) {
    ushort4 o;
    o.x = f2b(v[g * 4 + 0] * inv);
    o.y = f2b(v[g * 4 + 1] * inv);
    o.z = f2b(v[g * 4 + 2] * inv);
    o.w = f2b(v[g * 4 + 3] * inv);
    ((ushort4*)dst)[g * 64 + lane] = o;
  }
}

extern "C" void kernel_launch(void* const* d_in, const int* in_sizes, int n_in,
                              void* d_out, int out_size, void* d_ws, size_t ws_size,
                              hipStream_t stream) {
  const float* Xk = (const float*)d_in[0];
  const float* Xv = (const float*)d_in[1];
  const float* Xq = (const float*)d_in[2];
  const float* Wk = (const float*)d_in[3];
  const float* Wv = (const float*)d_in[4];
  const float* Wq = (const float*)d_in[5];
  float* out = (float*)d_out;

  // ws (ushort elems): S fp32 [0, 33.5M ushorts) aliases Wt+Xb (dead after proj);
  // then Qb | Kb | Vt. Peak 117.4 MB.
  unsigned short* ws = (unsigned short*)d_ws;
  float* S = (float*)d_ws;
  unsigned short* Wt = ws;
  unsigned short* Xb = ws + 3 * WE;
  unsigned short* Qb = ws + 33554432LL;
  unsigned short* Kb = Qb + XE;
  unsigned short* Vt = Kb + XE;

  cvt3<<<dim3(1024, 3), 256, 0, stream>>>(Xk, Xv, Xq, Xb);
  wcvt_t<<<dim3(16, 16, 3), 256, 0, stream>>>(Wk, Wv, Wq, Wt);

  proj8_kernel<<<dim3(32, 4, 3), 512, 131072, stream>>>(Xb, Wt, Kb, Vt, Qb);
  scores_kernel<<<dim3(136, 4), 256, 0, stream>>>(Qb, Kb, S);
  softmax_causal<<<2048, 256, 0, stream>>>(S);
  pv_kernel<<<dim3(32, 16), 256, 0, stream>>>((const unsigned short*)d_ws, Vt, out);
}